// Round 7
// baseline (653.441 us; speedup 1.0000x reference)
//
#include <hip/hip_runtime.h>
#include <cstdint>

#define BH  16
#define SEQ 2048
#define DIM 64
#define OUT_ELEMS (BH*SEQ*DIM)   // 2097152 floats; attn follows at this offset

typedef float f32x4 __attribute__((ext_vector_type(4)));
typedef float f32x2 __attribute__((ext_vector_type(2)));
typedef short bf16x8 __attribute__((ext_vector_type(8)));
typedef unsigned short u16;
typedef unsigned short u16x8 __attribute__((ext_vector_type(8)));

#define MFMA16 __builtin_amdgcn_mfma_f32_16x16x32_bf16

// ---- kB dynamic LDS layout (bytes) ----
// [S2 bf16 16 x 2056]      65792   P (exp values), padded rows: bank-shift 4 dw/row
// [vT  bf16 2 x 64 x 264]  67584   double-buffered v^T tiles (256 c each)
//   (phase-0 union: M fp32[4096], q fp32[1024], T fp32[1024] live in vT region)
// [red f32 8x16 | mrow 16 | linv 16]  640
#define S2_RS     2056
#define S2_BYTES  (16*S2_RS*2)
#define VT_RS     264
#define VT_HALVES (64*VT_RS)
#define VT_BYTES  (2*VT_HALVES*2)
#define LDS_BYTES (S2_BYTES + VT_BYTES + 640)   // 134016 -> 1 block/CU

__device__ __forceinline__ u16 f2bf(float x){            // RNE f32->bf16
  uint32_t u = __float_as_uint(x);
  return (u16)((u + 0x7fffu + ((u>>16)&1u)) >> 16);
}
__device__ __forceinline__ void split8(f32x4 a, f32x4 b, bf16x8& hi, bf16x8& lo){
  float v[8] = {a.x,a.y,a.z,a.w,b.x,b.y,b.z,b.w};
  #pragma unroll
  for (int i=0;i<8;i++){
    uint32_t u  = __float_as_uint(v[i]);
    uint32_t hb = u & 0xffff0000u;
    hi[i] = (short)(hb>>16);
    lo[i] = (short)f2bf(v[i] - __uint_as_float(hb));
  }
}

// ---------------- Kernel A: M += k^T q / 64 via fp32 atomics (M pre-zeroed) -------
__global__ __launch_bounds__(256) void kA(const float* __restrict__ kk,
                                          const float* __restrict__ qq,
                                          float* __restrict__ M){
  __shared__ __align__(16) float kl[64][68];
  __shared__ __align__(16) float ql[64][68];
  const int b   = blockIdx.y;
  const int ch  = blockIdx.x;            // 32 chunks of 64 rows
  const int tid = threadIdx.x;
  const int j     = tid & 63;
  const int ibase = (tid >> 6) * 16;     // wave-uniform
  const int lrow  = tid >> 2;
  const int lcol  = (tid & 3) * 16;
  const int l0    = ch * 64;
  const f32x4* ks = (const f32x4*)(kk + ((size_t)b*SEQ + l0 + lrow)*DIM + lcol);
  const f32x4* qs = (const f32x4*)(qq + ((size_t)b*SEQ + l0 + lrow)*DIM + lcol);
  f32x4 kv[4], qv[4];
  #pragma unroll
  for (int i=0;i<4;i++){ kv[i]=ks[i]; qv[i]=qs[i]; }
  #pragma unroll
  for (int i=0;i<4;i++){
    *(f32x4*)&kl[lrow][lcol+4*i] = kv[i];
    *(f32x4*)&ql[lrow][lcol+4*i] = qv[i];
  }
  __syncthreads();
  float acc[16];
  #pragma unroll
  for (int i=0;i<16;i++) acc[i]=0.f;
  for (int t=0; t<64; ++t){
    const float qv1 = ql[t][j];
    const f32x4 k0 = *(const f32x4*)&kl[t][ibase];
    const f32x4 k1 = *(const f32x4*)&kl[t][ibase+4];
    const f32x4 k2 = *(const f32x4*)&kl[t][ibase+8];
    const f32x4 k3 = *(const f32x4*)&kl[t][ibase+12];
    acc[0]+=k0.x*qv1; acc[1]+=k0.y*qv1; acc[2]+=k0.z*qv1; acc[3]+=k0.w*qv1;
    acc[4]+=k1.x*qv1; acc[5]+=k1.y*qv1; acc[6]+=k1.z*qv1; acc[7]+=k1.w*qv1;
    acc[8]+=k2.x*qv1; acc[9]+=k2.y*qv1; acc[10]+=k2.z*qv1; acc[11]+=k2.w*qv1;
    acc[12]+=k3.x*qv1; acc[13]+=k3.y*qv1; acc[14]+=k3.z*qv1; acc[15]+=k3.w*qv1;
  }
  float* mp = M + (size_t)b*4096;
  #pragma unroll
  for (int ii=0; ii<16; ++ii)
    atomicAdd(&mp[(ibase+ii)*64 + j], acc[ii] * (1.0f/64.0f));
}

// ---------------- Kernel B: MFMA persistent; register logits, dbuf PV -------------
__global__ __launch_bounds__(512,1) void kB(const float* __restrict__ q,
                                            const float* __restrict__ pos,
                                            const float* __restrict__ v,
                                            const float* __restrict__ M,
                                            float* __restrict__ outp,
                                            float* __restrict__ attn){
  extern __shared__ __align__(16) char smem[];
  u16*   S2   = (u16*)smem;                      // [16][S2_RS]
  u16*   vT   = (u16*)(smem + S2_BYTES);         // [2][64][VT_RS]
  float* Uf   = (float*)(smem + S2_BYTES);       // phase-0: M[4096] q[1024] T[1024]
  float* red  = (float*)(smem + S2_BYTES + VT_BYTES);  // [8][16]
  float* mrow = red + 128;                       // [16]
  float* linv = mrow + 16;                       // [16]
  float* qs   = Uf + 4096;
  float* Tl   = Uf + 5120;

  const int blk   = blockIdx.x;
  const int xcd   = blk & 7;
  const int slot  = blk >> 3;                    // 0..31
  const int b     = xcd*2 + (slot & 1);
  const int bslot = slot >> 1;                   // 0..15
  const int tid   = threadIdx.x;
  const int lane  = tid & 63;
  const int w     = tid >> 6;                    // 0..7
  const int quad  = lane >> 4;
  const int l16   = lane & 15;

  const float* pb = pos + (size_t)b*SEQ*DIM;
  const float* vb = v   + (size_t)b*SEQ*DIM;
  const float* qb = q   + (size_t)b*SEQ*DIM;
  const float* Mb = M   + (size_t)b*4096;

  for (int t = 0; t < 8; ++t){
    const int r0 = (bslot*8 + t) * 16;
    __syncthreads();                             // prev task's Pout/vT reads done

    // ---- phase 0: stage M + q, compute T = q*M ----
    {
      const f32x4* Mg = (const f32x4*)Mb;
      f32x4* Md = (f32x4*)Uf;
      Md[tid]     = Mg[tid];
      Md[tid+512] = Mg[tid+512];
      if (tid < 256)
        ((f32x4*)qs)[tid] = ((const f32x4*)(qb + (size_t)r0*DIM))[tid];
    }
    __syncthreads();
    {
      const int r = tid >> 5;                    // 0..15
      const int e = tid & 31;
      float a0 = 0.f, a1 = 0.f;
      #pragma unroll 8
      for (int d=0; d<64; ++d){
        const float qd = qs[r*64 + d];
        a0 += qd * Uf[d*64 + e];
        a1 += qd * Uf[d*64 + e + 32];
      }
      Tl[r*64 + e]      = a0;
      Tl[r*64 + e + 32] = a1;
    }
    __syncthreads();

    // ---- A-frags (T hi/lo), both k-halves ----
    bf16x8 Ah[2], Al[2];
    #pragma unroll
    for (int h=0; h<2; ++h){
      const float* ts = Tl + l16*64 + h*32 + quad*8;
      split8(*(const f32x4*)ts, *(const f32x4*)(ts+4), Ah[h], Al[h]);
    }

    // ---- logits in registers: wave w covers c-stripe [w*256, +256), no barriers ----
    f32x4 Sreg[16];
    {
      const float* pr = pb + (size_t)(w*256 + l16)*DIM + quad*8;
      f32x4 p0 = *(const f32x4*)pr;
      f32x4 p1 = *(const f32x4*)(pr+4);
      f32x4 p2 = *(const f32x4*)(pr+32);
      f32x4 p3 = *(const f32x4*)(pr+36);
      #pragma unroll
      for (int tt=0; tt<16; ++tt){
        f32x4 n0,n1,n2,n3;
        if (tt < 15){
          const float* pn = pb + (size_t)(w*256 + (tt+1)*16 + l16)*DIM + quad*8;
          n0 = *(const f32x4*)pn;
          n1 = *(const f32x4*)(pn+4);
          n2 = *(const f32x4*)(pn+32);
          n3 = *(const f32x4*)(pn+36);
        }
        bf16x8 Bh0, Bl0, Bh1, Bl1;
        split8(p0, p1, Bh0, Bl0);
        split8(p2, p3, Bh1, Bl1);
        f32x4 acc = {0.f,0.f,0.f,0.f};
        acc = MFMA16(Ah[0], Bh0, acc, 0,0,0);
        acc = MFMA16(Al[0], Bh0, acc, 0,0,0);
        acc = MFMA16(Ah[0], Bl0, acc, 0,0,0);
        acc = MFMA16(Ah[1], Bh1, acc, 0,0,0);
        acc = MFMA16(Al[1], Bh1, acc, 0,0,0);
        acc = MFMA16(Ah[1], Bl1, acc, 0,0,0);
        Sreg[tt] = acc;
        p0=n0; p1=n1; p2=n2; p3=n3;
      }
    }

    // ---- row max over regs -> shuffle over l16 -> cross-wave via red ----
    float mloc[4];
    #pragma unroll
    for (int i=0;i<4;i++) mloc[i] = -3.0e38f;
    #pragma unroll
    for (int tt=0; tt<16; ++tt)
      #pragma unroll
      for (int i=0;i<4;i++) mloc[i] = fmaxf(mloc[i], Sreg[tt][i]);
    #pragma unroll
    for (int i=0;i<4;i++){
      float m = mloc[i];
      m = fmaxf(m, __shfl_xor(m, 1, 64));
      m = fmaxf(m, __shfl_xor(m, 2, 64));
      m = fmaxf(m, __shfl_xor(m, 4, 64));
      m = fmaxf(m, __shfl_xor(m, 8, 64));
      if (l16 == 0) red[w*16 + quad*4 + i] = m;
    }
    __syncthreads();
    if (tid < 16){
      float m = red[tid];
      #pragma unroll
      for (int w2=1; w2<8; ++w2) m = fmaxf(m, red[w2*16 + tid]);
      mrow[tid] = m;
    }
    __syncthreads();

    // ---- exp in regs + row sums ----
    float mr[4], sloc[4];
    #pragma unroll
    for (int i=0;i<4;i++){ mr[i] = mrow[quad*4+i]; sloc[i] = 0.f; }
    #pragma unroll
    for (int tt=0; tt<16; ++tt)
      #pragma unroll
      for (int i=0;i<4;i++){
        const float e = __expf(Sreg[tt][i] - mr[i]);
        Sreg[tt][i] = e;
        sloc[i] += e;
      }
    #pragma unroll
    for (int i=0;i<4;i++){
      float s = sloc[i];
      s += __shfl_xor(s, 1, 64);
      s += __shfl_xor(s, 2, 64);
      s += __shfl_xor(s, 4, 64);
      s += __shfl_xor(s, 8, 64);
      if (l16 == 0) red[w*16 + quad*4 + i] = s;
    }
    __syncthreads();
    if (tid < 16){
      float s = red[tid];
      #pragma unroll
      for (int w2=1; w2<8; ++w2) s += red[w2*16 + tid];
      linv[tid] = 1.0f / s;
    }
    __syncthreads();

    // ---- attn = e*linv (NT, from regs) + P bf16 -> S2 ----
    {
      float li[4];
      #pragma unroll
      for (int i=0;i<4;i++) li[i] = linv[quad*4+i];
      float* ab = attn + ((size_t)b*SEQ + r0)*(size_t)SEQ;
      #pragma unroll
      for (int tt=0; tt<16; ++tt){
        const int c = w*256 + tt*16 + l16;
        #pragma unroll
        for (int i=0;i<4;i++){
          const int row = quad*4+i;
          __builtin_nontemporal_store(Sreg[tt][i]*li[i],
                                      ab + (size_t)row*SEQ + c);
          S2[row*S2_RS + c] = f2bf(Sreg[tt][i]);
        }
      }
    }
    __syncthreads();                             // P visible; Uf(T) dead -> vT free

    // ---- PV: 8 rounds of 256 c, double-buffered vT, 1 barrier/round ----
    const int khalf = w >> 2;                    // 0..1 (c-half within round)
    const int ntile = w & 3;                     // output d-tile
    const int c8 = (tid & 31) * 8;               // staging: 8 c's
    const int d4 = (tid >> 5) * 4;               // staging: 4 d's
    f32x4 pacc = {0.f,0.f,0.f,0.f};
    f32x4 cur[8];
    #pragma unroll
    for (int cc=0; cc<8; ++cc)
      cur[cc] = *(const f32x4*)(vb + (size_t)(c8+cc)*DIM + d4);
    #pragma unroll 1
    for (int r=0; r<8; ++r){
      f32x4 nxt[8];
      if (r < 7){
        #pragma unroll
        for (int cc=0; cc<8; ++cc)
          nxt[cc] = *(const f32x4*)(vb + (size_t)((r+1)*256 + c8 + cc)*DIM + d4);
      }
      u16* dst = vT + (r&1)*VT_HALVES;
      #pragma unroll
      for (int dd=0; dd<4; ++dd){
        u16x8 pk;
        #pragma unroll
        for (int cc=0; cc<8; ++cc) pk[cc] = f2bf(cur[cc][dd]);
        *(u16x8*)&dst[(d4+dd)*VT_RS + c8] = pk;
      }
      __syncthreads();
      const u16* vbuf = vT + (r&1)*VT_HALVES;
      #pragma unroll
      for (int kk=0; kk<4; ++kk){
        const int cb = khalf*128 + kk*32;
        const bf16x8 Af = *(const bf16x8*)&S2[l16*S2_RS + r*256 + cb + quad*8];
        const bf16x8 Bf = *(const bf16x8*)&vbuf[(ntile*16 + l16)*VT_RS + cb + quad*8];
        pacc = MFMA16(Af, Bf, pacc, 0,0,0);
      }
      #pragma unroll
      for (int cc=0; cc<8; ++cc) cur[cc] = nxt[cc];
    }
    __syncthreads();                             // all vT reads done
    {
      float* Pout = (float*)vT;                  // [8][16][16] overlay
      #pragma unroll
      for (int i=0;i<4;i++)
        Pout[w*256 + (quad*4+i)*16 + l16] = pacc[i];
    }
    __syncthreads();
    {
      const int o = tid*2;                       // 1024 outputs, 2/thread
      const int m = o >> 6;
      const int d = o & 63;
      const float* Pout = (const float*)vT;
      const int w_a = d >> 4, col = d & 15;
      float s0 = Pout[w_a*256 + m*16 + col]     + Pout[(w_a+4)*256 + m*16 + col];
      float s1 = Pout[w_a*256 + m*16 + col + 1] + Pout[(w_a+4)*256 + m*16 + col + 1];
      const float li = linv[m];
      f32x2 res; res.x = s0*li; res.y = s1*li;
      *(f32x2*)(outp + ((size_t)b*SEQ + r0 + m)*DIM + d) = res;
    }
  }
}

extern "C" void kernel_launch(void* const* d_in, const int* in_sizes, int n_in,
                              void* d_out, int out_size, void* d_ws, size_t ws_size,
                              hipStream_t stream){
  const float* q = (const float*)d_in[0];
  const float* k = (const float*)d_in[1];
  const float* v = (const float*)d_in[2];
  const float* p = (const float*)d_in[3];
  float* out  = (float*)d_out;
  float* attn = out + OUT_ELEMS;          // second tuple element
  float* M    = (float*)d_ws;             // 16*64*64 fp32 = 256 KB

  hipFuncSetAttribute((const void*)kB,
                      hipFuncAttributeMaxDynamicSharedMemorySize, LDS_BYTES);

  hipMemsetAsync(d_ws, 0, BH*4096*sizeof(float), stream);
  kA<<<dim3(32,16), 256, 0, stream>>>(k, q, M);
  kB<<<dim3(256),   512, LDS_BYTES, stream>>>(q, p, v, M, out, attn);
}